// Round 16
// baseline (19.877 us; speedup 1.0000x reference)
//
#include <hip/hip_runtime.h>
#include <hip/hip_bf16.h>

typedef _Float16 f16;
typedef f16 f16x2 __attribute__((ext_vector_type(2)));
typedef f16 f16x4 __attribute__((ext_vector_type(4)));
typedef f16 f16x8 __attribute__((ext_vector_type(8)));
typedef float f32x4 __attribute__((ext_vector_type(4)));

constexpr int B_  = 4;
constexpr int H_  = 128;
constexpr int W_  = 128;
constexpr int C_  = 64;
constexpr int NH_ = 4;
constexpr int D_  = 16;
constexpr int KK_ = 25;

constexpr int TW_  = 8, TH_ = 8;
constexpr int HWID = 12, HHEI = 12;
constexpr int NPX  = HHEI * HWID;          // 144 halo pixels
// LDS layout:
//   [0    , 18432) abuf  [144][64] f16, chunk-XOR swizzled; staged ref -> r in-place
//   [18432, 26624) mabuf [64][64]  f16; staged main -> q in-place
//   [26624, 39936) pxbuf [4][64][26] f16 probs (DEDICATED - no aliasing)
constexpr int MOFF  = NPX * 64 * 2;        // 18432
constexpr int POFF  = MOFF + 64 * 64 * 2;  // 26624
constexpr int PSTR  = KK_ + 1;             // 26 f16 (52B/px, 13 dwords: coprime 32)
constexpr int PSLAB = 64 * PSTR;           // 1664 f16
constexpr int SMEM  = POFF + NH_ * PSLAB * 2;  // 39936 <= 40960 -> 4 blocks/CU

#if __has_builtin(__builtin_amdgcn_fdot2)
#define FDOT2(a, b, c) __builtin_amdgcn_fdot2((a), (b), (c), false)
#else
#define FDOT2(a, b, c) fmaf((float)(a)[1], (float)(b)[1], fmaf((float)(a)[0], (float)(b)[0], (c)))
#endif

__device__ __forceinline__ int div12(int x) { return (x * 171) >> 11; }  // exact 0..143
__device__ __forceinline__ int div5(int x)  { return (x * 205) >> 10; }  // exact 0..24

__global__ __launch_bounds__(512, 8) void rl8mh16(
    const float* __restrict__ mainp, const float* __restrict__ refp,
    const float* __restrict__ wmain, const float* __restrict__ wref,
    float* __restrict__ out)
{
    __shared__ __align__(16) unsigned char smraw[SMEM];
    f16* abuf  = (f16*)smraw;             // staged ref halo -> rbuf in-place
    f16* mabuf = (f16*)(smraw + MOFF);    // staged main     -> qbuf in-place
    f16* pxbuf = (f16*)(smraw + POFF);    // probs (dedicated)

    const int tid = threadIdx.x;
    const int l   = tid & 63;
    const int wid = __builtin_amdgcn_readfirstlane(tid >> 6);  // 0..7
    const int n   = wid & 3;    // head (all phases)
    const int h   = wid >> 2;   // half (proj phase tile split)
    const int row = l & 15;
    const int kg  = l >> 4;

    // XCD-chunked swizzle (bijective, 256 % 8 == 0)
    const int bid = blockIdx.y * 16 + blockIdx.x;
    const int swz = (bid & 7) * 32 + (bid >> 3);
    const int x0 = (swz & 15) * TW_;
    const int y0 = (swz >> 4) * TH_;
    const int b  = blockIdx.z;
    const float* mainb = mainp + ((size_t)b * H_) * W_ * C_;
    const float* refb  = refp  + ((size_t)b * H_) * W_ * C_;

    // ---- Phase 0: coalesced staging, f32 -> f16, 16B-chunk XOR swizzle ----
    for (int j = tid; j < NPX * 16; j += 512) {
        int hp = j >> 4, c4 = j & 15;
        int hy = div12(hp), hx = hp - hy * HWID;
        int gy = y0 + hy - 2, gx = x0 + hx - 2;
        float4 v = make_float4(0.f, 0.f, 0.f, 0.f);
        if ((unsigned)gy < (unsigned)H_ && (unsigned)gx < (unsigned)W_)
            v = *(const float4*)(refb + ((size_t)gy * W_ + gx) * C_ + c4 * 4);
        f16x4 h4 = {(f16)v.x, (f16)v.y, (f16)v.z, (f16)v.w};
        int off = hp * 64 + ((((c4 >> 1) ^ (hp & 7)) << 3) | ((c4 & 1) << 2));
        *(f16x4*)(abuf + off) = h4;
    }
    for (int j = tid; j < 64 * 16; j += 512) {
        int px = j >> 4, c4 = j & 15;
        int gy = y0 + (px >> 3), gx = x0 + (px & 7);
        float4 v = *(const float4*)(mainb + ((size_t)gy * W_ + gx) * C_ + c4 * 4);
        f16x4 h4 = {(f16)v.x, (f16)v.y, (f16)v.z, (f16)v.w};
        int off = px * 64 + ((((c4 >> 1) ^ (px & 7)) << 3) | ((c4 & 1) << 2));
        *(f16x4*)(mabuf + off) = h4;
    }
    __syncthreads();   // bar1

    // ---- weight fragment build (A-operand of swapped MFMA), AFTER staging ----
    auto build_w = [&](const float* wsrc, f16x8* A) {
        const float* w = wsrc + n * C_ * D_;
        #pragma unroll
        for (int s = 0; s < 2; ++s) {
            union { f16x8 v; f16 e[8]; } u;
            #pragma unroll
            for (int i = 0; i < 8; ++i)
                u.e[i] = (f16)w[(s * 32 + kg * 8 + i) * D_ + row];
            A[s] = u.v;
        }
    };

    // ---- Phase 1: projections into registers (swapped MFMA: lane = pixel) ----
    auto proj = [&](const f16* src, int t, const f16x8* A) -> f16x4 {
        int px = t * 16 + row;
        const f16* rp = src + px * 64;
        f16x8 B0 = *(const f16x8*)(rp + (((kg     ^ (px & 7)) << 3)));
        f16x8 B1 = *(const f16x8*)(rp + ((((kg+4) ^ (px & 7)) << 3)));
        f32x4 acc = {0.f, 0.f, 0.f, 0.f};
        acc = __builtin_amdgcn_mfma_f32_16x16x32_f16(A[0], B0, acc, 0, 0, 0);
        acc = __builtin_amdgcn_mfma_f32_16x16x32_f16(A[1], B1, acc, 0, 0, 0);
        return f16x4{(f16)acc[0], (f16)acc[1], (f16)acc[2], (f16)acc[3]};
    };
    f16x4 racc0, racc1, racc2, racc3, racc4, qacc0, qacc1;
    {
        f16x8 ar[2];
        build_w(wref, ar);
        if (h == 0) {
            racc0 = proj(abuf, 0, ar); racc1 = proj(abuf, 2, ar);
            racc2 = proj(abuf, 4, ar); racc3 = proj(abuf, 6, ar);
            racc4 = proj(abuf, 8, ar);
        } else {
            racc0 = proj(abuf, 1, ar); racc1 = proj(abuf, 3, ar);
            racc2 = proj(abuf, 5, ar); racc3 = proj(abuf, 7, ar);
        }
    }
    {
        f16x8 am[2];
        build_w(wmain, am);
        if (h == 0) { qacc0 = proj(mabuf, 0, am); qacc1 = proj(mabuf, 2, am); }
        else        { qacc0 = proj(mabuf, 1, am); qacc1 = proj(mabuf, 3, am); }
    }
    __syncthreads();   // bar2: all staging reads done -> safe to overwrite

    // ---- Phase 2: write r/q in-place (lane holds d = kg*4..+3 of its pixel) ----
    auto wrout = [&](f16* dst, int t, f16x4 v) {
        int px = t * 16 + row;
        int c16 = (n << 1) | (kg >> 1);
        int off = px * 64 + (((c16 ^ (px & 7)) << 3) | ((kg & 1) << 2));
        *(f16x4*)(dst + off) = v;
    };
    if (h == 0) {
        wrout(abuf, 0, racc0); wrout(abuf, 2, racc1); wrout(abuf, 4, racc2);
        wrout(abuf, 6, racc3); wrout(abuf, 8, racc4);
        wrout(mabuf, 0, qacc0); wrout(mabuf, 2, qacc1);
    } else {
        wrout(abuf, 1, racc0); wrout(abuf, 3, racc1); wrout(abuf, 5, racc2);
        wrout(abuf, 7, racc3);
        wrout(mabuf, 1, qacc0); wrout(mabuf, 3, qacc1);
    }
    __syncthreads();   // bar3: rbuf/qbuf ready

    // ==== Epilogue remap: lane = (hh = l>>5, px = pbase + (l&31)) ====
    const int pbase = (wid >> 2) * 32;        // px half owned by this wave
    const int px  = pbase + (l & 31);
    const int hh  = l >> 5;
    const int py  = px >> 3;
    const int pxx = px & 7;

    // q fragment (lanes l and l+32 read same px -> LDS broadcast)
    f16x8 q0 = *(const f16x8*)(mabuf + px * 64 + ((((n << 1) | 0) ^ (px & 7)) << 3));
    f16x8 q1 = *(const f16x8*)(mabuf + px * 64 + ((((n << 1) | 1) ^ (px & 7)) << 3));
    const f16x2* q2a = (const f16x2*)&q0;
    const f16x2* q2b = (const f16x2*)&q1;

    // logits: uniform path, k = hh*12 + j (hh=1 duplicates k=12, fixed in sum)
    float lg[13];
    #pragma unroll
    for (int j = 0; j < 13; ++j) {
        int k  = hh * 12 + j;
        int ky = div5(k);
        int kx = k - 5 * ky;
        int np = (py + ky) * 12 + pxx + kx;
        const f16* rp = abuf + np * 64;
        f16x8 r0 = *(const f16x8*)(rp + ((((n << 1) | 0) ^ (np & 7)) << 3));
        f16x8 r1 = *(const f16x8*)(rp + ((((n << 1) | 1) ^ (np & 7)) << 3));
        const f16x2* r2a = (const f16x2*)&r0;
        const f16x2* r2b = (const f16x2*)&r1;
        float a = 0.f;
        #pragma unroll
        for (int jj = 0; jj < 4; ++jj) a = FDOT2(q2a[jj], r2a[jj], a);
        #pragma unroll
        for (int jj = 0; jj < 4; ++jj) a = FDOT2(q2b[jj], r2b[jj], a);
        lg[j] = a;
    }

    // softmax halves merged via shfl_xor(32) — no LDS, no barrier
    float mloc = lg[0];
    #pragma unroll
    for (int j = 1; j < 13; ++j) mloc = fmaxf(mloc, lg[j]);
    float s = 0.f;
    #pragma unroll
    for (int j = 0; j < 13; ++j) { lg[j] = __expf(lg[j] - mloc); s += lg[j]; }
    float s_own = hh ? (s - lg[0]) : s;      // hh=1: k=12 counted by hh=0
    float om = __shfl_xor(mloc, 32);
    float os = __shfl_xor(s_own, 32);
    float m   = fmaxf(mloc, om);
    float sc  = __expf(mloc - m);
    float osc = __expf(om - m);
    float inv = sc / (s_own * sc + os * osc);

    // probs -> dedicated f16 buffer (no alias -> no fence needed before write)
    {   // hh=1's j=0 (k=12) duplicates hh=0's value — benign near-identical race
        f16* dst = pxbuf + n * PSLAB + px * PSTR + hh * 12;
        #pragma unroll
        for (int j = 0; j < 13; ++j) dst[j] = (f16)(lg[j] * inv);
    }
    __syncthreads();   // bar4: probs ready

    // ---- head-average + store ----
    for (int i = tid; i < TW_ * TH_ * KK_; i += 512) {
        int p2 = i / KK_;
        int k  = i - p2 * KK_;
        int off = p2 * PSTR + k;
        float v = 0.25f * ((float)pxbuf[off]
                         + (float)pxbuf[PSLAB + off]
                         + (float)pxbuf[2 * PSLAB + off]
                         + (float)pxbuf[3 * PSLAB + off]);
        out[(((size_t)b * H_ + (y0 + (p2 >> 3))) * W_ + (x0 + (p2 & 7))) * KK_ + k] = v;
    }
}

extern "C" void kernel_launch(void* const* d_in, const int* in_sizes, int n_in,
                              void* d_out, int out_size, void* d_ws, size_t ws_size,
                              hipStream_t stream) {
    const float* mainp = (const float*)d_in[0];
    const float* refp  = (const float*)d_in[1];
    const float* wmain = (const float*)d_in[2];
    const float* wref  = (const float*)d_in[3];
    float* outp = (float*)d_out;

    dim3 grid(W_ / TW_, H_ / TH_, B_);
    rl8mh16<<<grid, dim3(512), 0, stream>>>(mainp, refp, wmain, wref, outp);
}